// Round 5
// baseline (520.308 us; speedup 1.0000x reference)
//
#include <hip/hip_runtime.h>
#include <math.h>
#include <float.h>
#include <limits.h>

#define N 8192
#define D 64
#define TOPK 32
#define TILE 128
#define CAP 1024

typedef __attribute__((ext_vector_type(8))) short short8;
typedef __attribute__((ext_vector_type(4))) float float4v;

// orderable-uint encoding of float: a > b  <=>  ford(a) > ford(b)
__device__ __forceinline__ unsigned ford(float f) {
    unsigned u = __float_as_uint(f);
    return u ^ ((u & 0x80000000u) ? 0xFFFFFFFFu : 0x80000000u);
}
__device__ __forceinline__ float finv(unsigned u) {
    unsigned b = (u & 0x80000000u) ? (u ^ 0x80000000u) : ~u;
    return __uint_as_float(b);
}
// round-to-nearest-even fp32 -> bf16 bits
__device__ __forceinline__ unsigned short bf16rne(float f) {
    unsigned u = __float_as_uint(f);
    return (unsigned short)((u + 0x7FFFu + ((u >> 16) & 1u)) >> 16);
}
__device__ __forceinline__ float bf2f(unsigned short h) {
    return __uint_as_float((unsigned)h << 16);
}

// ---------------------------------------------------------------------------
// Kernel 1: row norms of X1 and X2 -> nrm[0..2N)
// ---------------------------------------------------------------------------
__global__ __launch_bounds__(256) void norms_kernel(
    const float* __restrict__ X1, const float* __restrict__ X2,
    float* __restrict__ nrm)
{
    int id = blockIdx.x * blockDim.x + threadIdx.x;
    if (id >= 2 * N) return;
    const float* X = (id < N) ? X1 : X2;
    int r = (id < N) ? id : id - N;
    const float4* p = (const float4*)(X + (size_t)r * D);
    float s = 0.f;
#pragma unroll
    for (int q = 0; q < D / 4; ++q) {
        float4 v = p[q];
        s += v.x * v.x + v.y * v.y + v.z * v.z + v.w * v.w;
    }
    nrm[id] = s;
}

// ---------------------------------------------------------------------------
// Kernel 2 (MFMA): 3-way bf16 split (hi+mid+lo, residual 2^-27) GEMM via
// mfma_f32_16x16x32_bf16; 6 products hh,hm,mh,hl,lh,mm => fp32-class error.
// 128x128 tile/block, 4 waves, each wave a 64x64 quadrant = 4x4 MFMA tiles.
// LDS: 6 split arrays, 16B-chunk XOR swizzle (chunkpos = c ^ (row&7)).
// Stores -max(sq,0) (monotone proxy; sqrt applied to winners in topk).
// ---------------------------------------------------------------------------
__global__ __launch_bounds__(256, 1) void dist_kernel(
    const float* __restrict__ X1, const float* __restrict__ X2,
    const float* __restrict__ nrm, float* __restrict__ dst,
    float* __restrict__ tmax, int have_tmax)
{
    __shared__ __align__(16) short Ah[128 * 64], Am[128 * 64], Al[128 * 64];
    __shared__ __align__(16) short Bh[128 * 64], Bm[128 * 64], Bl[128 * 64];
    __shared__ float tpart[128][2];

    const int t = threadIdx.x;
    const int row0 = blockIdx.y * TILE;
    const int col0 = blockIdx.x * TILE;

    // ---- stage: fp32 -> (hi,mid,lo) bf16 splits in LDS ----
#pragma unroll
    for (int q = 0; q < 8; ++q) {
        int g  = q * 256 + t;          // chunk id 0..2047 (A:0..1023, B:1024..)
        int mtx = g >> 10;             // 0=A, 1=B
        int gg = g & 1023;
        int rr = gg >> 3;              // row 0..127
        int cc = gg & 7;               // 16B chunk within row
        const float* src = (mtx ? X2 : X1) +
                           (size_t)((mtx ? col0 : row0) + rr) * D + 8 * cc;
        float4 xa = *(const float4*)src;
        float4 xb = *(const float4*)(src + 4);
        float xs[8] = {xa.x, xa.y, xa.z, xa.w, xb.x, xb.y, xb.z, xb.w};
        short8 hv, mv, lv;
#pragma unroll
        for (int j = 0; j < 8; ++j) {
            float f = xs[j];
            unsigned short h = bf16rne(f);
            float rm = f - bf2f(h);
            unsigned short m = bf16rne(rm);
            float rl = rm - bf2f(m);
            unsigned short l = bf16rne(rl);
            hv[j] = (short)h; mv[j] = (short)m; lv[j] = (short)l;
        }
        int off = rr * 8 + (cc ^ (rr & 7));
        if (mtx == 0) {
            ((short8*)Ah)[off] = hv; ((short8*)Am)[off] = mv; ((short8*)Al)[off] = lv;
        } else {
            ((short8*)Bh)[off] = hv; ((short8*)Bm)[off] = mv; ((short8*)Bl)[off] = lv;
        }
    }
    __syncthreads();

    const int w     = t >> 6;
    const int lane  = t & 63;
    const int RW    = (w >> 1) * 64;
    const int CW    = (w & 1) * 64;
    const int rq    = lane >> 4;    // k-chunk selector / row-quad for C
    const int rlow  = lane & 15;    // M/N index within 16-tile

    float4v acc[4][4];
#pragma unroll
    for (int i = 0; i < 4; ++i)
#pragma unroll
        for (int j = 0; j < 4; ++j)
            acc[i][j] = (float4v){0.f, 0.f, 0.f, 0.f};

#pragma unroll
    for (int ks = 0; ks < 2; ++ks) {           // K = 64 in two 32-chunks
        const int cidx = 4 * ks + rq;          // chunk = (8k-group)
        short8 bh[4], bm[4], bl[4];
#pragma unroll
        for (int tn = 0; tn < 4; ++tn) {
            int rr = CW + 16 * tn + rlow;
            int off = rr * 8 + (cidx ^ (rr & 7));
            bh[tn] = ((const short8*)Bh)[off];
            bm[tn] = ((const short8*)Bm)[off];
            bl[tn] = ((const short8*)Bl)[off];
        }
#pragma unroll
        for (int tm = 0; tm < 4; ++tm) {
            int rr = RW + 16 * tm + rlow;
            int off = rr * 8 + (cidx ^ (rr & 7));
            short8 ah = ((const short8*)Ah)[off];
            short8 am = ((const short8*)Am)[off];
            short8 al = ((const short8*)Al)[off];
#pragma unroll
            for (int tn = 0; tn < 4; ++tn) {
                float4v c = acc[tm][tn];
                c = __builtin_amdgcn_mfma_f32_16x16x32_bf16(ah, bh[tn], c, 0, 0, 0);
                c = __builtin_amdgcn_mfma_f32_16x16x32_bf16(ah, bm[tn], c, 0, 0, 0);
                c = __builtin_amdgcn_mfma_f32_16x16x32_bf16(am, bh[tn], c, 0, 0, 0);
                c = __builtin_amdgcn_mfma_f32_16x16x32_bf16(ah, bl[tn], c, 0, 0, 0);
                c = __builtin_amdgcn_mfma_f32_16x16x32_bf16(al, bh[tn], c, 0, 0, 0);
                c = __builtin_amdgcn_mfma_f32_16x16x32_bf16(am, bm[tn], c, 0, 0, 0);
                acc[tm][tn] = c;
            }
        }
    }

    // ---- epilogue: sq -> -max(sq,0), store, per-row maxes ----
    float na[4][4], nb[4];
#pragma unroll
    for (int tm = 0; tm < 4; ++tm)
#pragma unroll
        for (int reg = 0; reg < 4; ++reg)
            na[tm][reg] = nrm[row0 + RW + 16 * tm + 4 * rq + reg];
#pragma unroll
    for (int tn = 0; tn < 4; ++tn)
        nb[tn] = nrm[N + col0 + CW + 16 * tn + rlow];

    float rmx[4][4];
#pragma unroll
    for (int tm = 0; tm < 4; ++tm)
#pragma unroll
        for (int reg = 0; reg < 4; ++reg)
            rmx[tm][reg] = -FLT_MAX;

#pragma unroll
    for (int tm = 0; tm < 4; ++tm) {
#pragma unroll
        for (int tn = 0; tn < 4; ++tn) {
#pragma unroll
            for (int reg = 0; reg < 4; ++reg) {
                int row_local = RW + 16 * tm + 4 * rq + reg;
                int col_local = CW + 16 * tn + rlow;
                float sq = na[tm][reg] + nb[tn] - 2.0f * acc[tm][tn][reg];
                float v = -fmaxf(sq, 0.0f);
                dst[(size_t)(row0 + row_local) * N + col0 + col_local] = v;
                rmx[tm][reg] = fmaxf(rmx[tm][reg], v);
            }
        }
    }

    if (have_tmax) {
#pragma unroll
        for (int tm = 0; tm < 4; ++tm) {
#pragma unroll
            for (int reg = 0; reg < 4; ++reg) {
                float mv = rmx[tm][reg];
                mv = fmaxf(mv, __shfl_xor(mv, 1));
                mv = fmaxf(mv, __shfl_xor(mv, 2));
                mv = fmaxf(mv, __shfl_xor(mv, 4));
                mv = fmaxf(mv, __shfl_xor(mv, 8));
                if (rlow == 0)
                    tpart[RW + 16 * tm + 4 * rq + reg][w & 1] = mv;
            }
        }
        __syncthreads();
        if ((w & 1) == 0) {
            int row_abs = RW + lane;          // lanes 0..63 cover the 64 rows
            float tv = fmaxf(tpart[row_abs][0], tpart[row_abs][1]);
            tmax[(size_t)(row0 + row_abs) * 64 + blockIdx.x] = tv;
        }
    }
}

// ---------------------------------------------------------------------------
// Kernel 3: one wave per row. thr = 32nd-largest tile-max (sound). STREAM all
// 64 tiles coalesced (batched x4 float4), push survivors >= thr to per-wave
// LDS keys, write zeros to out inline, 32x shfl argmax, sqrt+softmax, scatter.
// ---------------------------------------------------------------------------
__global__ __launch_bounds__(256) void topk_kernel(
    const float* __restrict__ src, float* __restrict__ out,
    float* __restrict__ score_out, const float* __restrict__ tmax,
    int have_tmax)
{
    __shared__ unsigned long long cand[4][CAP];   // 32 KB
    __shared__ int scnt[4];

    const int t    = threadIdx.x;
    const int w    = t >> 6;
    const int lane = t & 63;
    const int r    = blockIdx.x * 4 + w;
    const float4* row4 = (const float4*)(src + (size_t)r * N);
    float* rowout = out + (size_t)r * N;

    // ---- threshold ----
    float thr;
    if (have_tmax) {
        float tm = tmax[(size_t)r * 64 + lane];
        unsigned km = ford(tm);
        int rk = 0;
#pragma unroll
        for (int l = 0; l < 64; ++l) {
            unsigned o = __shfl(km, l);
            rk += (o > km || (o == km && l < lane)) ? 1 : 0;
        }
        unsigned long long bm = __ballot(rk == 31);
        thr = __shfl(tm, __ffsll((long long)bm) - 1);
    } else {
        float lm = -FLT_MAX;
#pragma unroll 8
        for (int c = 0; c < 32; ++c) {
            float4 x = row4[c * 64 + lane];
            lm = fmaxf(lm, fmaxf(fmaxf(x.x, x.y), fmaxf(x.z, x.w)));
        }
        thr = lm;   // min of per-lane maxes: sound (>=64 survivors)
        for (int off = 32; off > 0; off >>= 1)
            thr = fminf(thr, __shfl_xor(thr, off));
    }

    if (lane == 0) scnt[w] = 0;
    __builtin_amdgcn_s_waitcnt(0xC07F);   // lgkmcnt(0)

    // ---- stream + compact + zero-fill out ----
    const float4 zz = make_float4(0.f, 0.f, 0.f, 0.f);
    for (int c0 = 0; c0 < 32; c0 += 4) {
        float4 xs[4];
#pragma unroll
        for (int u = 0; u < 4; ++u) xs[u] = row4[(c0 + u) * 64 + lane];
#pragma unroll
        for (int u = 0; u < 4; ++u) ((float4*)rowout)[(c0 + u) * 64 + lane] = zz;
#pragma unroll
        for (int u = 0; u < 4; ++u) {
            float vs[4] = {xs[u].x, xs[u].y, xs[u].z, xs[u].w};
#pragma unroll
            for (int q = 0; q < 4; ++q) {
                float v = vs[q];
                if (v >= thr) {
                    int p = atomicAdd(&scnt[w], 1);
                    if (p < CAP) {   // expected survivors ~44 << CAP
                        int j = 4 * ((c0 + u) * 64 + lane) + q;
                        cand[w][p] = ((unsigned long long)ford(v) << 32) |
                                     (unsigned)(8191 - j);
                    }
                }
            }
        }
    }
    __builtin_amdgcn_s_waitcnt(0xC07F);   // lgkmcnt(0): pushes visible
    const int n = min(scnt[w], CAP);

    // ---- 32 x wave argmax over packed keys (value desc, index asc) ----
    unsigned long long mykey = 0ull;
    for (int it = 0; it < TOPK; ++it) {
        unsigned long long b = 0ull; int bp = 0;
        for (int q = lane; q < n; q += 64) {
            unsigned long long kk = cand[w][q];
            if (kk > b) { b = kk; bp = q; }
        }
        for (int off = 32; off > 0; off >>= 1) {
            unsigned long long ob = __shfl_down(b, off);
            int op = __shfl_down(bp, off);
            if (ob > b) { b = ob; bp = op; }
        }
        unsigned long long b0 = __shfl(b, 0);
        int bp0 = __shfl(bp, 0);
        if (lane == it) { mykey = b0; cand[w][bp0] = 0ull; }
    }

    // ---- sqrt + softmax on the 32 winners (rank == lane) ----
    float myv = 0.f; int myj = 0;
    if (lane < TOPK) {
        float sv = finv((unsigned)(mykey >> 32));   // stored -max(sq,0)
        myv = -sqrtf(-sv);
        myj = 8191 - (int)(mykey & 0xFFFFFFFFu);
    }
    float Mx = __shfl(myv, 0);
    float e = (lane < TOPK) ? expf(myv - Mx) : 0.f;
    float Z = e;
    for (int off = 32; off > 0; off >>= 1) Z += __shfl_xor(Z, off);
    float s = e / Z;
    if (lane < TOPK) score_out[(size_t)r * TOPK + lane] = s;

    __builtin_amdgcn_s_waitcnt(0x0F70);   // vmcnt(0): zeros drained
    if (lane < TOPK) rowout[myj] = s;
}

// ---------------------------------------------------------------------------
extern "C" void kernel_launch(void* const* d_in, const int* in_sizes, int n_in,
                              void* d_out, int out_size, void* d_ws, size_t ws_size,
                              hipStream_t stream)
{
    const float* X1 = (const float*)d_in[0];
    const float* X2 = (const float*)d_in[1];
    float* out  = (float*)d_out;
    float* nrm  = (float*)d_ws;                 // 2N floats
    float* tmax = nrm + 2 * N;                  // N*64 floats
    float* dmat = tmax + (size_t)N * 64;        // N*N floats (256 MB)

    size_t need_tmax = (size_t)(2 * N + (size_t)N * 64) * sizeof(float);
    size_t need_full = need_tmax + (size_t)N * N * sizeof(float);
    int have_tmax = (ws_size >= need_tmax) ? 1 : 0;
    int fastmode  = (ws_size >= need_full) ? 1 : 0;

    float* dst = fastmode ? dmat : out;

    norms_kernel<<<(2 * N + 255) / 256, 256, 0, stream>>>(X1, X2, nrm);

    dim3 grid(N / TILE, N / TILE);
    dist_kernel<<<grid, 256, 0, stream>>>(X1, X2, nrm, dst, tmax, have_tmax);

    topk_kernel<<<N / 4, 256, 0, stream>>>(dst, out, out + (size_t)N * N,
                                           tmax, have_tmax && fastmode);
}